// Round 1
// baseline (10878.564 us; speedup 1.0000x reference)
//
#include <hip/hip_runtime.h>
#include <hip/hip_bf16.h>
#include <math.h>

// Problem constants
#define B_   2048
#define T_   256
#define E_   124
#define V_   65
#define E2_  248   // 2E
#define E3_  372   // 3E
#define R_   8     // batch rows per block
#define NT_  512   // threads per block
#define NB_  (B_ / R_)   // 256 blocks
#define KB_IH 62   // 248/4 k-blocks for gi
#define KB_HH 31   // 124/4 k-blocks for gh / cand / head
#define CSPLIT 140 // j < CSPLIT: gh done by helper thread (tid = 372 + j)

// LDS layout (float offsets)
#define U_STRIDE 384
#define OFF_U      0                 // 8*384 = 3072
#define OFF_GI     3072              // 372*9 = 3348 (stride 9: bank-conflict pad)
#define OFF_GH     6420              // 3348
#define OFF_WM     9768              // 124*124 = 15376
#define OFF_WHEAD  25144             // 65*124 = 8060
#define OFF_HNEW   33204             // 8*124 = 992
#define OFF_Y      34196             // 992
#define OFF_BIH    35188             // 372
#define OFF_BHH    35560             // 372
#define OFF_BM     35932             // 124
#define OFF_WP     36056             // 124
#define OFF_LNG    36180             // 124
#define OFF_LNB    36304             // 124
#define OFF_BHEAD  36428             // 65
#define OFF_P      36493             // 8
#define OFF_MU     36501             // 8
#define OFF_RS     36509             // 8
#define SMEM_FLOATS 36520
#define SMEM_BYTES (SMEM_FLOATS * 4)

__device__ __forceinline__ float sigmoid_f(float x) {
    return 1.0f / (1.0f + __expf(-x));
}
__device__ __forceinline__ float tanh_f(float x) {
    // 2*sigmoid(2x)-1 ; safe at both infinities (no NaN)
    return 2.0f / (1.0f + __expf(-2.0f * x)) - 1.0f;
}

// Transpose weights into k-blocked layouts:
//   WihT[(kb*372 + j)*4 + i] = w_ih[j*248 + kb*4 + i]   (kb in [0,62))
//   WhhT[(kb*372 + j)*4 + i] = w_hh[j*124 + kb*4 + i]   (kb in [0,31))
__global__ void prep_weights(const float* __restrict__ w_ih,
                             const float* __restrict__ w_hh,
                             float* __restrict__ ws) {
    const int n1 = KB_IH * E3_ * 4;  // 92256
    const int n2 = KB_HH * E3_ * 4;  // 46128
    for (int n = blockIdx.x * blockDim.x + threadIdx.x; n < n1 + n2;
         n += gridDim.x * blockDim.x) {
        if (n < n1) {
            int kb = n / (E3_ * 4);
            int rem = n - kb * (E3_ * 4);
            int j = rem >> 2, i = rem & 3;
            ws[n] = w_ih[j * E2_ + kb * 4 + i];
        } else {
            int m = n - n1;
            int kb = m / (E3_ * 4);
            int rem = m - kb * (E3_ * 4);
            int j = rem >> 2, i = rem & 3;
            ws[n] = w_hh[j * E_ + kb * 4 + i];
        }
    }
}

__global__ void __launch_bounds__(NT_, 1)
gru_main(const int* __restrict__ idx, const float* __restrict__ tok,
         const float* __restrict__ pos,
         const float* __restrict__ b_ih, const float* __restrict__ b_hh,
         const float* __restrict__ w_p, const float* __restrict__ b_p,
         const float* __restrict__ w_m, const float* __restrict__ b_m,
         const float* __restrict__ ln_g, const float* __restrict__ ln_b,
         const float* __restrict__ w_head, const float* __restrict__ b_head,
         const float* __restrict__ ws, float* __restrict__ out) {
    extern __shared__ float sm[];
    const int tid = threadIdx.x;
    const int b0 = blockIdx.x * R_;
    const float* __restrict__ WihT = ws;
    const float* __restrict__ WhhT = ws + KB_IH * E3_ * 4;

    // ---- one-time staging ----
    for (int i = tid; i < E_ * E_; i += NT_) sm[OFF_WM + i] = w_m[i];
    for (int i = tid; i < V_ * E_; i += NT_) sm[OFF_WHEAD + i] = w_head[i];
    for (int i = tid; i < E3_; i += NT_) {
        sm[OFF_BIH + i] = b_ih[i];
        sm[OFF_BHH + i] = b_hh[i];
    }
    for (int i = tid; i < E_; i += NT_) {
        sm[OFF_BM + i] = b_m[i];
        sm[OFF_WP + i] = w_p[i];
        sm[OFF_LNG + i] = ln_g[i];
        sm[OFF_LNB + i] = ln_b[i];
    }
    for (int i = tid; i < V_; i += NT_) sm[OFF_BHEAD + i] = b_head[i];
    for (int i = tid; i < R_ * U_STRIDE; i += NT_) sm[OFF_U + i] = 0.0f;  // h=m=0
    const float bp = b_p[0];
    __syncthreads();

    for (int t = 0; t < T_; ++t) {
        // ---- P1: x_t = token_emb[idx] + pos_emb[t]  -> u[r][0:124] ----
        for (int i = tid; i < R_ * E_; i += NT_) {
            int r = i / E_, e = i - r * E_;
            int token = idx[(b0 + r) * T_ + t];
            sm[OFF_U + r * U_STRIDE + e] = tok[token * E_ + e] + pos[t * E_ + e];
        }
        __syncthreads();

        // ---- P2: gi[j] (248-dot over [x;m]) and gh[j] (124-dot over h) ----
        {
            bool do_gi = false, do_gh = false;
            int j = 0;
            if (tid < E3_) {
                j = tid;
                do_gi = true;
                do_gh = (j >= CSPLIT);
            } else if (tid < E3_ + CSPLIT) {
                j = tid - E3_;
                do_gh = true;
            }
            if (do_gi) {
                float acc[R_];
#pragma unroll
                for (int r = 0; r < R_; ++r) acc[r] = 0.0f;
                for (int kb = 0; kb < KB_IH; ++kb) {
                    const float4 w = *(const float4*)&WihT[(kb * E3_ + j) * 4];
#pragma unroll
                    for (int r = 0; r < R_; ++r) {
                        const float4 uv =
                            *(const float4*)&sm[OFF_U + r * U_STRIDE + kb * 4];
                        acc[r] += w.x * uv.x + w.y * uv.y + w.z * uv.z + w.w * uv.w;
                    }
                }
                const float bb = sm[OFF_BIH + j];
#pragma unroll
                for (int r = 0; r < R_; ++r) sm[OFF_GI + j * 9 + r] = acc[r] + bb;
            }
            if (do_gh) {
                float acc[R_];
#pragma unroll
                for (int r = 0; r < R_; ++r) acc[r] = 0.0f;
                for (int kb = 0; kb < KB_HH; ++kb) {
                    const float4 w = *(const float4*)&WhhT[(kb * E3_ + j) * 4];
#pragma unroll
                    for (int r = 0; r < R_; ++r) {
                        const float4 uv =
                            *(const float4*)&sm[OFF_U + r * U_STRIDE + E2_ + kb * 4];
                        acc[r] += w.x * uv.x + w.y * uv.y + w.z * uv.z + w.w * uv.w;
                    }
                }
                const float bb = sm[OFF_BHH + j];
#pragma unroll
                for (int r = 0; r < R_; ++r) sm[OFF_GH + j * 9 + r] = acc[r] + bb;
            }
        }
        __syncthreads();

        // ---- P3: gates -> h_new ----
        for (int i = tid; i < R_ * E_; i += NT_) {
            int r = i / E_, e = i - r * E_;
            float ir = sm[OFF_GI + e * 9 + r], hr = sm[OFF_GH + e * 9 + r];
            float iz = sm[OFF_GI + (E_ + e) * 9 + r], hz = sm[OFF_GH + (E_ + e) * 9 + r];
            float in_ = sm[OFF_GI + (E2_ + e) * 9 + r], hn = sm[OFF_GH + (E2_ + e) * 9 + r];
            float rg = sigmoid_f(ir + hr);
            float z = sigmoid_f(iz + hz);
            float nn = tanh_f(in_ + rg * hn);
            float hold = sm[OFF_U + r * U_STRIDE + E2_ + e];
            sm[OFF_HNEW + r * E_ + e] = (1.0f - z) * nn + z * hold;
        }
        __syncthreads();

        // ---- P4: p = sigmoid(h_new . w_p + b_p); LN stats ----
        if (tid < 128) {
            int r = tid >> 4, g = tid & 15;
            float s = 0.0f;
            for (int k = g; k < E_; k += 16)
                s += sm[OFF_HNEW + r * E_ + k] * sm[OFF_WP + k];
            s += __shfl_xor(s, 1);
            s += __shfl_xor(s, 2);
            s += __shfl_xor(s, 4);
            s += __shfl_xor(s, 8);
            if (g == 0) sm[OFF_P + r] = sigmoid_f(s + bp);
        } else if (tid < 256) {
            int r = (tid - 128) >> 4, g = tid & 15;
            float s1 = 0.0f, s2 = 0.0f;
            for (int k = g; k < E_; k += 16) {
                float h = sm[OFF_HNEW + r * E_ + k];
                s1 += h;
                s2 += h * h;
            }
            s1 += __shfl_xor(s1, 1);
            s1 += __shfl_xor(s1, 2);
            s1 += __shfl_xor(s1, 4);
            s1 += __shfl_xor(s1, 8);
            s2 += __shfl_xor(s2, 1);
            s2 += __shfl_xor(s2, 2);
            s2 += __shfl_xor(s2, 4);
            s2 += __shfl_xor(s2, 8);
            if (g == 0) {
                float mu = s1 * (1.0f / (float)E_);
                float var = s2 * (1.0f / (float)E_) - mu * mu;
                sm[OFF_MU + r] = mu;
                sm[OFF_RS + r] = rsqrtf(var + 1e-5f);
            }
        }
        __syncthreads();

        // ---- P5: cand, m update, h commit, y = LN(h_new) ----
        for (int i = tid; i < R_ * E_; i += NT_) {
            int r = i / E_, e = i - r * E_;
            float acc = sm[OFF_BM + e];
            for (int kb = 0; kb < KB_HH; ++kb) {
                float4 w = *(const float4*)&sm[OFF_WM + e * E_ + kb * 4];
                float4 h4 = *(const float4*)&sm[OFF_HNEW + r * E_ + kb * 4];
                acc += w.x * h4.x + w.y * h4.y + w.z * h4.z + w.w * h4.w;
            }
            float cand = tanh_f(acc);
            float pv = sm[OFF_P + r];
            float mold = sm[OFF_U + r * U_STRIDE + E_ + e];
            sm[OFF_U + r * U_STRIDE + E_ + e] = (1.0f - pv) * mold + pv * cand;
            float hv = sm[OFF_HNEW + r * E_ + e];
            sm[OFF_U + r * U_STRIDE + E2_ + e] = hv;  // commit h for next step
            sm[OFF_Y + r * E_ + e] =
                (hv - sm[OFF_MU + r]) * sm[OFF_RS + r] * sm[OFF_LNG + e] + sm[OFF_LNB + e];
        }
        __syncthreads();

        // ---- P6: head logits -> global ----
        for (int i = tid; i < R_ * V_; i += NT_) {
            int r = i / V_, v = i - r * V_;
            float acc = sm[OFF_BHEAD + v];
            for (int kb = 0; kb < KB_HH; ++kb) {
                float4 w = *(const float4*)&sm[OFF_WHEAD + v * E_ + kb * 4];
                float4 y4 = *(const float4*)&sm[OFF_Y + r * E_ + kb * 4];
                acc += w.x * y4.x + w.y * y4.y + w.z * y4.z + w.w * y4.w;
            }
            out[((b0 + r) * T_ + t) * V_ + v] = acc;
        }
        // no barrier needed: next-iter P1 touches only u[x], and barrier after P1
        // orders P6 reads (y_s) before any later overwrite.
        __syncthreads();
    }
}

extern "C" void kernel_launch(void* const* d_in, const int* in_sizes, int n_in,
                              void* d_out, int out_size, void* d_ws, size_t ws_size,
                              hipStream_t stream) {
    const int* idx = (const int*)d_in[0];
    const float* tok = (const float*)d_in[1];
    const float* pos = (const float*)d_in[2];
    const float* w_ih = (const float*)d_in[3];
    const float* w_hh = (const float*)d_in[4];
    const float* b_ih = (const float*)d_in[5];
    const float* b_hh = (const float*)d_in[6];
    const float* w_p = (const float*)d_in[7];
    const float* b_p = (const float*)d_in[8];
    const float* w_m = (const float*)d_in[9];
    const float* b_m = (const float*)d_in[10];
    const float* ln_g = (const float*)d_in[11];
    const float* ln_b = (const float*)d_in[12];
    const float* w_head = (const float*)d_in[13];
    const float* b_head = (const float*)d_in[14];
    float* out = (float*)d_out;
    float* ws = (float*)d_ws;

    // transpose/k-block the recurrent weights into workspace (553,536 bytes)
    prep_weights<<<541, 256, 0, stream>>>(w_ih, w_hh, ws);

    // allow >64KB dynamic LDS
    (void)hipFuncSetAttribute((const void*)gru_main,
                              hipFuncAttributeMaxDynamicSharedMemorySize,
                              SMEM_BYTES);
    gru_main<<<NB_, NT_, SMEM_BYTES, stream>>>(idx, tok, pos, b_ih, b_hh, w_p, b_p,
                                               w_m, b_m, ln_g, ln_b, w_head, b_head,
                                               ws, out);
}

// Round 2
// 8944.404 us; speedup vs baseline: 1.2162x; 1.2162x over previous
//
#include <hip/hip_runtime.h>
#include <hip/hip_bf16.h>
#include <math.h>

// Problem constants
#define B_   2048
#define T_   256
#define E_   124
#define V_   65
#define E2_  248   // 2E
#define E3_  372   // 3E
#define R_   4     // batch rows per block
#define NT_  512   // threads per block
#define NB_  (B_ / R_)   // 512 blocks -> 2 blocks/CU
#define KB_IH 62   // 248/4 k-blocks
#define KB_HH 31   // 124/4 k-blocks

// ws layout (float offsets) — all weights k-blocked: W[(kb*ncols + col)*4 + i]
#define WS_IH  0
#define N_IH   (KB_IH * E3_ * 4)   // 92256
#define WS_HH  (N_IH)
#define N_HH   (KB_HH * E3_ * 4)   // 46128
#define WS_M   (WS_HH + N_HH)      // 138384
#define N_M    (KB_HH * E_ * 4)    // 15376
#define WS_HD  (WS_M + N_M)        // 153760
#define N_HD   (KB_HH * V_ * 4)    // 8060
#define WS_TOT (WS_HD + N_HD)      // 161820 floats = 647 KB

// LDS layout (float offsets), total 65,104 B -> 2 blocks/CU (130 KB <= 160 KB)
#define U_STRIDE 384
#define OFF_U     0        // 4*384 = 1536   u = [x(124) | m(124) | h(124)]
#define OFF_GI    1536     // 372*4 = 1488 (float4 per column: 4 rows)
#define OFF_GH    3024     // 1488
#define OFF_GHB   4512     // 92*4 = 368 (partial sums for split gh columns)
#define OFF_HNEW  4880     // 496
#define OFF_Y     5376     // 496
#define OFF_TOK   5872     // 65*124 = 8060 (full token_emb)
#define OFF_IDX   13932    // 4*256 ints = 1024
#define OFF_BIH   14956    // 372
#define OFF_BHH   15328    // 372
#define OFF_BM    15700    // 124
#define OFF_WP    15824    // 124
#define OFF_LNG   15948    // 124
#define OFF_LNB   16072    // 124
#define OFF_BHEAD 16196    // 65 (pad to 68)
#define OFF_P     16264    // 4
#define OFF_MU    16268    // 4
#define OFF_RS    16272    // 4
#define SMEM_FLOATS 16276
#define SMEM_BYTES (SMEM_FLOATS * 4)

__device__ __forceinline__ float sigmoid_f(float x) {
    return 1.0f / (1.0f + __expf(-x));
}
__device__ __forceinline__ float tanh_f(float x) {
    return 2.0f / (1.0f + __expf(-2.0f * x)) - 1.0f;
}

// k-block all four weight matrices into ws
__global__ void prep_weights(const float* __restrict__ w_ih,
                             const float* __restrict__ w_hh,
                             const float* __restrict__ w_m,
                             const float* __restrict__ w_head,
                             float* __restrict__ ws) {
    for (int n = blockIdx.x * blockDim.x + threadIdx.x; n < WS_TOT;
         n += gridDim.x * blockDim.x) {
        if (n < N_IH) {
            int kb = n / (E3_ * 4);
            int rem = n - kb * (E3_ * 4);
            int j = rem >> 2, i = rem & 3;
            ws[n] = w_ih[j * E2_ + kb * 4 + i];
        } else if (n < WS_M) {
            int m = n - WS_HH;
            int kb = m / (E3_ * 4);
            int rem = m - kb * (E3_ * 4);
            int j = rem >> 2, i = rem & 3;
            ws[n] = w_hh[j * E_ + kb * 4 + i];
        } else if (n < WS_HD) {
            int m = n - WS_M;
            int kb = m / (E_ * 4);
            int rem = m - kb * (E_ * 4);
            int e = rem >> 2, i = rem & 3;
            ws[n] = w_m[e * E_ + kb * 4 + i];
        } else {
            int m = n - WS_HD;
            int kb = m / (V_ * 4);
            int rem = m - kb * (V_ * 4);
            int v = rem >> 2, i = rem & 3;
            ws[n] = w_head[v * E_ + kb * 4 + i];
        }
    }
}

#define FMA4(acc, w, u) \
    acc += (w).x * (u).x + (w).y * (u).y + (w).z * (u).z + (w).w * (u).w

__global__ void __launch_bounds__(NT_, 4)
gru_main(const int* __restrict__ idx, const float* __restrict__ tok,
         const float* __restrict__ pos,
         const float* __restrict__ b_ih, const float* __restrict__ b_hh,
         const float* __restrict__ w_p, const float* __restrict__ b_p,
         const float* __restrict__ b_m,
         const float* __restrict__ ln_g, const float* __restrict__ ln_b,
         const float* __restrict__ b_head,
         const float* __restrict__ ws, float* __restrict__ out) {
    extern __shared__ float sm[];
    const int tid = threadIdx.x;
    const int b0 = blockIdx.x * R_;
    int* idxs = (int*)&sm[OFF_IDX];
    const float4* __restrict__ Wih4 = (const float4*)(ws + WS_IH);
    const float4* __restrict__ Whh4 = (const float4*)(ws + WS_HH);
    const float4* __restrict__ Wm4  = (const float4*)(ws + WS_M);
    const float4* __restrict__ Whd4 = (const float4*)(ws + WS_HD);

    // ---- one-time staging ----
    for (int i = tid; i < V_ * E_; i += NT_) sm[OFF_TOK + i] = tok[i];
    for (int i = tid; i < R_ * T_; i += NT_) idxs[i] = idx[b0 * T_ + i];
    for (int i = tid; i < E3_; i += NT_) {
        sm[OFF_BIH + i] = b_ih[i];
        sm[OFF_BHH + i] = b_hh[i];
    }
    for (int i = tid; i < E_; i += NT_) {
        sm[OFF_BM + i] = b_m[i];
        sm[OFF_WP + i] = w_p[i];
        sm[OFF_LNG + i] = ln_g[i];
        sm[OFF_LNB + i] = ln_b[i];
    }
    for (int i = tid; i < V_; i += NT_) sm[OFF_BHEAD + i] = b_head[i];
    for (int i = tid; i < R_ * U_STRIDE; i += NT_) sm[OFF_U + i] = 0.0f;  // h=m=0
    const float bp = b_p[0];
    __syncthreads();

    // ---- P1 for t=0 ----
    for (int i = tid; i < R_ * E_; i += NT_) {
        int r = i / E_, e = i - r * E_;
        int token = idxs[r * T_];
        sm[OFF_U + r * U_STRIDE + e] = sm[OFF_TOK + token * E_ + e] + pos[e];
    }
    __syncthreads();

    for (int t = 0; t < T_; ++t) {
        // ================= P2: gi (372 cols, 62 kb) + gh (372 cols, 31 kb) ==
        if (tid < E3_) {
            const int j = tid;
            float a0 = 0.f, a1 = 0.f, a2 = 0.f, a3 = 0.f;
#pragma unroll 2
            for (int kb = 0; kb < KB_IH; ++kb) {
                const float4 w = Wih4[kb * E3_ + j];
                const float4 u0 = *(const float4*)&sm[OFF_U + 0 * U_STRIDE + kb * 4];
                const float4 u1 = *(const float4*)&sm[OFF_U + 1 * U_STRIDE + kb * 4];
                const float4 u2 = *(const float4*)&sm[OFF_U + 2 * U_STRIDE + kb * 4];
                const float4 u3 = *(const float4*)&sm[OFF_U + 3 * U_STRIDE + kb * 4];
                FMA4(a0, w, u0);
                FMA4(a1, w, u1);
                FMA4(a2, w, u2);
                FMA4(a3, w, u3);
            }
            const float bb = sm[OFF_BIH + j];
            *(float4*)&sm[OFF_GI + j * 4] =
                make_float4(a0 + bb, a1 + bb, a2 + bb, a3 + bb);
            // balanced extra: half-columns of gh cols 280..371
            if (j < 184) {
                const int half = (j >= 92) ? 1 : 0;
                const int col = 280 + (half ? j - 92 : j);
                const int kb0 = half ? 16 : 0;
                const int kb1 = half ? KB_HH : 16;
                float c0 = 0.f, c1 = 0.f, c2 = 0.f, c3 = 0.f;
                for (int kb = kb0; kb < kb1; ++kb) {
                    const float4 w = Whh4[kb * E3_ + col];
                    const float4 u0 = *(const float4*)&sm[OFF_U + 0 * U_STRIDE + E2_ + kb * 4];
                    const float4 u1 = *(const float4*)&sm[OFF_U + 1 * U_STRIDE + E2_ + kb * 4];
                    const float4 u2 = *(const float4*)&sm[OFF_U + 2 * U_STRIDE + E2_ + kb * 4];
                    const float4 u3 = *(const float4*)&sm[OFF_U + 3 * U_STRIDE + E2_ + kb * 4];
                    FMA4(c0, w, u0);
                    FMA4(c1, w, u1);
                    FMA4(c2, w, u2);
                    FMA4(c3, w, u3);
                }
                if (!half) {
                    const float bb2 = sm[OFF_BHH + col];
                    *(float4*)&sm[OFF_GH + col * 4] =
                        make_float4(c0 + bb2, c1 + bb2, c2 + bb2, c3 + bb2);
                } else {
                    *(float4*)&sm[OFF_GHB + (j - 92) * 4] = make_float4(c0, c1, c2, c3);
                }
            }
        } else {
            const int s = tid - E3_;  // 0..139: gh cols s and s+140 (covers 0..279)
#pragma unroll
            for (int c = 0; c < 2; ++c) {
                const int col = s + c * 140;
                float c0 = 0.f, c1 = 0.f, c2 = 0.f, c3 = 0.f;
#pragma unroll 2
                for (int kb = 0; kb < KB_HH; ++kb) {
                    const float4 w = Whh4[kb * E3_ + col];
                    const float4 u0 = *(const float4*)&sm[OFF_U + 0 * U_STRIDE + E2_ + kb * 4];
                    const float4 u1 = *(const float4*)&sm[OFF_U + 1 * U_STRIDE + E2_ + kb * 4];
                    const float4 u2 = *(const float4*)&sm[OFF_U + 2 * U_STRIDE + E2_ + kb * 4];
                    const float4 u3 = *(const float4*)&sm[OFF_U + 3 * U_STRIDE + E2_ + kb * 4];
                    FMA4(c0, w, u0);
                    FMA4(c1, w, u1);
                    FMA4(c2, w, u2);
                    FMA4(c3, w, u3);
                }
                const float bb = sm[OFF_BHH + col];
                *(float4*)&sm[OFF_GH + col * 4] =
                    make_float4(c0 + bb, c1 + bb, c2 + bb, c3 + bb);
            }
        }
        __syncthreads();

        // ================= P3: gates -> h_new =================
        if (tid < R_ * E_) {
            const int r = tid / E_, e = tid - (tid / E_) * E_;
            const float ir = sm[OFF_GI + e * 4 + r];
            const float iz = sm[OFF_GI + (E_ + e) * 4 + r];
            const float in_ = sm[OFF_GI + (E2_ + e) * 4 + r];
            const float hr = sm[OFF_GH + e * 4 + r];
            const float hz = sm[OFF_GH + (E_ + e) * 4 + r];
            float hn = sm[OFF_GH + (E2_ + e) * 4 + r];
            if (e >= 32) hn += sm[OFF_GHB + (e - 32) * 4 + r];
            const float rg = sigmoid_f(ir + hr);
            const float z = sigmoid_f(iz + hz);
            const float nn = tanh_f(in_ + rg * hn);
            const float hold = sm[OFF_U + r * U_STRIDE + E2_ + e];
            sm[OFF_HNEW + r * E_ + e] = (1.0f - z) * nn + z * hold;
        }
        __syncthreads();

        // ===== P4 (p-gate dot + LN stats, 2 waves) overlapped with cand matvec =====
        float cand_r = 0.f;
        {
            if (tid < 64) {
                const int r = tid >> 4, g = tid & 15;
                float s = 0.f;
                for (int k = g; k < E_; k += 16)
                    s += sm[OFF_HNEW + r * E_ + k] * sm[OFF_WP + k];
                s += __shfl_xor(s, 1);
                s += __shfl_xor(s, 2);
                s += __shfl_xor(s, 4);
                s += __shfl_xor(s, 8);
                if (g == 0) sm[OFF_P + r] = sigmoid_f(s + bp);
            } else if (tid < 128) {
                const int r = (tid - 64) >> 4, g = tid & 15;
                float s1 = 0.f, s2 = 0.f;
                for (int k = g; k < E_; k += 16) {
                    float h = sm[OFF_HNEW + r * E_ + k];
                    s1 += h;
                    s2 += h * h;
                }
                s1 += __shfl_xor(s1, 1);
                s1 += __shfl_xor(s1, 2);
                s1 += __shfl_xor(s1, 4);
                s1 += __shfl_xor(s1, 8);
                s2 += __shfl_xor(s2, 1);
                s2 += __shfl_xor(s2, 2);
                s2 += __shfl_xor(s2, 4);
                s2 += __shfl_xor(s2, 8);
                if (g == 0) {
                    float mu = s1 * (1.0f / (float)E_);
                    float var = s2 * (1.0f / (float)E_) - mu * mu;
                    sm[OFF_MU + r] = mu;
                    sm[OFF_RS + r] = rsqrtf(var + 1e-5f);
                }
            }
            if (tid < R_ * E_) {
                const int r = tid / E_, e = tid - (tid / E_) * E_;
                float acc = sm[OFF_BM + e];
#pragma unroll 2
                for (int kb = 0; kb < KB_HH; ++kb) {
                    const float4 w = Wm4[kb * E_ + e];
                    const float4 h4 = *(const float4*)&sm[OFF_HNEW + r * E_ + kb * 4];
                    FMA4(acc, w, h4);
                }
                cand_r = tanh_f(acc);
            }
        }
        __syncthreads();

        // ================= P5: m update, h commit, y = LN(h_new) =============
        if (tid < R_ * E_) {
            const int r = tid / E_, e = tid - (tid / E_) * E_;
            const float pv = sm[OFF_P + r];
            const float mold = sm[OFF_U + r * U_STRIDE + E_ + e];
            sm[OFF_U + r * U_STRIDE + E_ + e] = (1.0f - pv) * mold + pv * cand_r;
            const float hv = sm[OFF_HNEW + r * E_ + e];
            sm[OFF_U + r * U_STRIDE + E2_ + e] = hv;
            sm[OFF_Y + r * E_ + e] = (hv - sm[OFF_MU + r]) * sm[OFF_RS + r] *
                                         sm[OFF_LNG + e] + sm[OFF_LNB + e];
        }
        __syncthreads();

        // ========== P6: head logits (260 thr) || P1' for t+1 (252 thr) =======
        if (tid < R_ * V_) {
            const int r = tid / V_, v = tid - (tid / V_) * V_;
            float acc = sm[OFF_BHEAD + v];
#pragma unroll 2
            for (int kb = 0; kb < KB_HH; ++kb) {
                const float4 w = Whd4[kb * V_ + v];
                const float4 y4 = *(const float4*)&sm[OFF_Y + r * E_ + kb * 4];
                FMA4(acc, w, y4);
            }
            __builtin_nontemporal_store(
                acc, &out[((size_t)(b0 + r) * T_ + t) * V_ + v]);
        } else if (t + 1 < T_) {
            for (int i = tid - R_ * V_; i < R_ * E_; i += NT_ - R_ * V_) {
                const int r = i / E_, e = i - (i / E_) * E_;
                const int token = idxs[r * T_ + t + 1];
                sm[OFF_U + r * U_STRIDE + e] =
                    sm[OFF_TOK + token * E_ + e] + pos[(t + 1) * E_ + e];
            }
        }
        __syncthreads();
    }
}

extern "C" void kernel_launch(void* const* d_in, const int* in_sizes, int n_in,
                              void* d_out, int out_size, void* d_ws, size_t ws_size,
                              hipStream_t stream) {
    const int* idx = (const int*)d_in[0];
    const float* tok = (const float*)d_in[1];
    const float* pos = (const float*)d_in[2];
    const float* w_ih = (const float*)d_in[3];
    const float* w_hh = (const float*)d_in[4];
    const float* b_ih = (const float*)d_in[5];
    const float* b_hh = (const float*)d_in[6];
    const float* w_p = (const float*)d_in[7];
    const float* b_p = (const float*)d_in[8];
    const float* w_m = (const float*)d_in[9];
    const float* b_m = (const float*)d_in[10];
    const float* ln_g = (const float*)d_in[11];
    const float* ln_b = (const float*)d_in[12];
    const float* w_head = (const float*)d_in[13];
    const float* b_head = (const float*)d_in[14];
    float* out = (float*)d_out;
    float* ws = (float*)d_ws;

    prep_weights<<<640, 256, 0, stream>>>(w_ih, w_hh, w_m, w_head, ws);

    (void)hipFuncSetAttribute((const void*)gru_main,
                              hipFuncAttributeMaxDynamicSharedMemorySize,
                              SMEM_BYTES);
    gru_main<<<NB_, NT_, SMEM_BYTES, stream>>>(idx, tok, pos, b_ih, b_hh, w_p, b_p,
                                               b_m, ln_g, ln_b, b_head, ws, out);
}

// Round 3
// 3242.963 us; speedup vs baseline: 3.3545x; 2.7581x over previous
//
#include <hip/hip_runtime.h>
#include <math.h>

// Problem constants
#define B_   2048
#define T_   256
#define E_   124
#define V_   65
#define E2_  248
#define E3_  372
#define R_   16              // batch rows per block (MFMA M)
#define NT_  512             // 8 waves
#define NB_  (B_ / R_)       // 128 blocks

// fragment geometry (16x16x32 MFMA tiles)
#define GI_NT 24   // 384 cols  (372 padded)
#define GI_NC 8    // K=256     (248 padded)
#define GH_NT 24
#define GH_NC 4    // K=128     (124 padded)
#define WM_NT 8    // 128 cols
#define WM_NC 4
#define HD_NT 5    // 80 cols   (65 padded)
#define HD_NC 4

// ws offsets (in unsigned short elements); each frag block = 512 bf16 = 1KB
#define WS_GI 0
#define WS_GH (WS_GI + 2 * GI_NT * GI_NC * 512)   // 196608
#define WS_WM (WS_GH + 2 * GH_NT * GH_NC * 512)   // 294912
#define WS_HD (WS_WM + 2 * WM_NT * WM_NC * 512)   // 327680
#define WS_END (WS_HD + 2 * HD_NT * HD_NC * 512)  // 348160 shorts = 680KB

// LDS byte offsets (all 16B aligned)
#define USTR 264   // u row stride in shorts (248+pad; 528B -> 4-bank row step, 2-way max)
#define HSTR 136   // h/y row stride in shorts (272B -> 4-bank step)
#define GSTR 21    // gate buffer col stride in floats (odd -> conflict-free scalar r/w)
#define L_U1 0
#define L_U2 8448
#define L_H1 16896
#define L_H2 21248
#define L_Y1 25600
#define L_Y2 29952
#define L_GI 34304              // 384*21*4 = 32256
#define L_GH 66560              // 32256
#define L_BSUM 98816            // 248 f
#define L_BIN  99808            // 124 f
#define L_BHN  100304
#define L_BM   100800
#define L_WP   101296
#define L_LNG  101792
#define L_LNB  102288
#define L_BHD  102784           // 65 f (pad)
#define L_P    103056           // 16 f
#define L_MU   103120
#define L_RS   103184
#define L_IDX  103248           // 16*256 int = 16384
#define SMEM_BYTES 119632

typedef __attribute__((ext_vector_type(8))) short short8v;
typedef __attribute__((ext_vector_type(4))) float float4v;

__device__ __forceinline__ unsigned short f2bf(float x) {
    unsigned u = __float_as_uint(x);
    unsigned r = (u + 0x7fffu + ((u >> 16) & 1u)) >> 16;
    return (unsigned short)r;
}
__device__ __forceinline__ float bf2f(unsigned short s) {
    return __uint_as_float(((unsigned)s) << 16);
}
__device__ __forceinline__ float sigmoid_f(float x) {
    return 1.0f / (1.0f + __expf(-x));
}
__device__ __forceinline__ float tanh_f(float x) {
    return 2.0f / (1.0f + __expf(-2.0f * x)) - 1.0f;
}

// Build bf16 split-2 B-fragments for all weight matrices.
// Frag block (mat, split, tile, chunk): 512 bf16; lane l, reg j holds
// W[col = tile*16 + (l&15)][k = chunk*32 + (l>>4)*8 + j]  (zero-padded).
__global__ void prep_weights(const float* __restrict__ w_ih,
                             const float* __restrict__ w_hh,
                             const float* __restrict__ w_m,
                             const float* __restrict__ w_head,
                             unsigned short* __restrict__ ws) {
    for (int n = blockIdx.x * blockDim.x + threadIdx.x; n < WS_END;
         n += gridDim.x * blockDim.x) {
        int base, nc, nt, Kreal, Creal, ld;
        const float* src;
        if (n < WS_GH)      { base = WS_GI; nc = GI_NC; nt = GI_NT; Kreal = E2_; Creal = E3_; ld = E2_; src = w_ih; }
        else if (n < WS_WM) { base = WS_GH; nc = GH_NC; nt = GH_NT; Kreal = E_;  Creal = E3_; ld = E_;  src = w_hh; }
        else if (n < WS_HD) { base = WS_WM; nc = WM_NC; nt = WM_NT; Kreal = E_;  Creal = E_;  ld = E_;  src = w_m; }
        else                { base = WS_HD; nc = HD_NC; nt = HD_NT; Kreal = E_;  Creal = V_;  ld = E_;  src = w_head; }
        int m = n - base;
        int blk = m >> 9, r9 = m & 511;
        int lane = r9 >> 3, j = r9 & 7;
        int c = blk % nc;
        int rest = blk / nc;
        int tile = rest % nt;
        int split = rest / nt;
        int k = c * 32 + (lane >> 4) * 8 + j;
        int col = tile * 16 + (lane & 15);
        float w = (k < Kreal && col < Creal) ? src[col * ld + k] : 0.0f;
        unsigned short w1 = f2bf(w);
        ws[n] = (split == 0) ? w1 : f2bf(w - bf2f(w1));
    }
}

__global__ void __launch_bounds__(NT_, 2)
gru_main(const int* __restrict__ idx, const float* __restrict__ tok,
         const float* __restrict__ pos,
         const float* __restrict__ b_ih, const float* __restrict__ b_hh,
         const float* __restrict__ w_p, const float* __restrict__ b_p,
         const float* __restrict__ b_m,
         const float* __restrict__ ln_g, const float* __restrict__ ln_b,
         const float* __restrict__ b_head,
         const unsigned short* __restrict__ ws, float* __restrict__ out) {
    extern __shared__ char smraw[];
    unsigned short* U1 = (unsigned short*)(smraw + L_U1);
    unsigned short* U2 = (unsigned short*)(smraw + L_U2);
    unsigned short* H1 = (unsigned short*)(smraw + L_H1);
    unsigned short* H2 = (unsigned short*)(smraw + L_H2);
    unsigned short* Y1 = (unsigned short*)(smraw + L_Y1);
    unsigned short* Y2 = (unsigned short*)(smraw + L_Y2);
    float* GIb = (float*)(smraw + L_GI);
    float* GHb = (float*)(smraw + L_GH);
    float* BSUM = (float*)(smraw + L_BSUM);
    float* BIN = (float*)(smraw + L_BIN);
    float* BHN = (float*)(smraw + L_BHN);
    float* BM = (float*)(smraw + L_BM);
    float* WP = (float*)(smraw + L_WP);
    float* LNG = (float*)(smraw + L_LNG);
    float* LNB = (float*)(smraw + L_LNB);
    float* BHD = (float*)(smraw + L_BHD);
    float* Pp = (float*)(smraw + L_P);
    float* MU = (float*)(smraw + L_MU);
    float* RS = (float*)(smraw + L_RS);
    int* IDX = (int*)(smraw + L_IDX);

    const int tid = threadIdx.x;
    const int lane = tid & 63;
    const int wv = tid >> 6;
    const int b0 = blockIdx.x * R_;
    const int frow = lane & 15;   // A row / B col / C col
    const int fgrp = lane >> 4;   // k-group / C row-group

    // ---- one-time staging ----
    for (int i = tid; i < E2_; i += NT_) BSUM[i] = b_ih[i] + b_hh[i];
    for (int i = tid; i < E_; i += NT_) {
        BIN[i] = b_ih[E2_ + i];
        BHN[i] = b_hh[E2_ + i];
        BM[i] = b_m[i];
        WP[i] = w_p[i];
        LNG[i] = ln_g[i];
        LNB[i] = ln_b[i];
    }
    for (int i = tid; i < V_; i += NT_) BHD[i] = b_head[i];
    for (int i = tid; i < R_ * T_; i += NT_) IDX[i] = idx[b0 * T_ + i];
    for (int i = tid; i < R_ * USTR; i += NT_) { U1[i] = 0; U2[i] = 0; }
    for (int i = tid; i < R_ * HSTR; i += NT_) { H1[i] = 0; H2[i] = 0; Y1[i] = 0; Y2[i] = 0; }
    const float bp = b_p[0];
    __syncthreads();

    // embed t=0 into u[x]
    for (int i = tid; i < R_ * E_; i += NT_) {
        int r = i / E_, e = i - r * E_;
        int token = IDX[r * T_];
        float x = tok[token * E_ + e] + pos[e];
        unsigned short x1 = f2bf(x);
        U1[r * USTR + e] = x1;
        U2[r * USTR + e] = f2bf(x - bf2f(x1));
    }
    __syncthreads();

    for (int t = 0; t <= T_; ++t) {
        // =========== phase A: gate MFMAs (t<T) + head MFMA for t-1 ==========
        if (t < T_) {
            float4v acc[3], accg[3];
#pragma unroll
            for (int ti = 0; ti < 3; ++ti) {
                acc[ti] = (float4v){0.f, 0.f, 0.f, 0.f};
                accg[ti] = (float4v){0.f, 0.f, 0.f, 0.f};
            }
            // gi: u @ w_ih^T  (K=256, split-2)
#pragma unroll
            for (int c = 0; c < GI_NC; ++c) {
                short8v a1 = *(const short8v*)&U1[frow * USTR + c * 32 + fgrp * 8];
                short8v a2 = *(const short8v*)&U2[frow * USTR + c * 32 + fgrp * 8];
#pragma unroll
                for (int ti = 0; ti < 3; ++ti) {
                    const int tile = wv * 3 + ti;
                    short8v bw1 = *(const short8v*)&ws[WS_GI + ((0 * GI_NT + tile) * GI_NC + c) * 512 + lane * 8];
                    short8v bw2 = *(const short8v*)&ws[WS_GI + ((1 * GI_NT + tile) * GI_NC + c) * 512 + lane * 8];
                    acc[ti] = __builtin_amdgcn_mfma_f32_16x16x32_bf16(a1, bw1, acc[ti], 0, 0, 0);
                    acc[ti] = __builtin_amdgcn_mfma_f32_16x16x32_bf16(a2, bw1, acc[ti], 0, 0, 0);
                    acc[ti] = __builtin_amdgcn_mfma_f32_16x16x32_bf16(a1, bw2, acc[ti], 0, 0, 0);
                }
            }
            // gh: h @ w_hh^T  (K=128, split-2)
#pragma unroll
            for (int c = 0; c < GH_NC; ++c) {
                short8v a1 = *(const short8v*)&H1[frow * HSTR + c * 32 + fgrp * 8];
                short8v a2 = *(const short8v*)&H2[frow * HSTR + c * 32 + fgrp * 8];
#pragma unroll
                for (int ti = 0; ti < 3; ++ti) {
                    const int tile = wv * 3 + ti;
                    short8v bw1 = *(const short8v*)&ws[WS_GH + ((0 * GH_NT + tile) * GH_NC + c) * 512 + lane * 8];
                    short8v bw2 = *(const short8v*)&ws[WS_GH + ((1 * GH_NT + tile) * GH_NC + c) * 512 + lane * 8];
                    accg[ti] = __builtin_amdgcn_mfma_f32_16x16x32_bf16(a1, bw1, accg[ti], 0, 0, 0);
                    accg[ti] = __builtin_amdgcn_mfma_f32_16x16x32_bf16(a2, bw1, accg[ti], 0, 0, 0);
                    accg[ti] = __builtin_amdgcn_mfma_f32_16x16x32_bf16(a1, bw2, accg[ti], 0, 0, 0);
                }
            }
            // write C fragments (scalar stores, odd stride -> conflict-free)
#pragma unroll
            for (int ti = 0; ti < 3; ++ti) {
                const int col = (wv * 3 + ti) * 16 + frow;
#pragma unroll
                for (int j = 0; j < 4; ++j) {
                    GIb[col * GSTR + fgrp * 4 + j] = acc[ti][j];
                    GHb[col * GSTR + fgrp * 4 + j] = accg[ti][j];
                }
            }
        }
        // head for step t-1 (y ready from phase D of t-1)
        if (t > 0 && wv < HD_NT) {
            float4v ah = (float4v){0.f, 0.f, 0.f, 0.f};
#pragma unroll
            for (int c = 0; c < HD_NC; ++c) {
                short8v a1 = *(const short8v*)&Y1[frow * HSTR + c * 32 + fgrp * 8];
                short8v a2 = *(const short8v*)&Y2[frow * HSTR + c * 32 + fgrp * 8];
                short8v bw1 = *(const short8v*)&ws[WS_HD + ((0 * HD_NT + wv) * HD_NC + c) * 512 + lane * 8];
                short8v bw2 = *(const short8v*)&ws[WS_HD + ((1 * HD_NT + wv) * HD_NC + c) * 512 + lane * 8];
                ah = __builtin_amdgcn_mfma_f32_16x16x32_bf16(a1, bw1, ah, 0, 0, 0);
                ah = __builtin_amdgcn_mfma_f32_16x16x32_bf16(a2, bw1, ah, 0, 0, 0);
                ah = __builtin_amdgcn_mfma_f32_16x16x32_bf16(a1, bw2, ah, 0, 0, 0);
            }
            const int v = wv * 16 + frow;
            if (v < V_) {
                const float bh = BHD[v];
#pragma unroll
                for (int j = 0; j < 4; ++j) {
                    const int row = fgrp * 4 + j;
                    out[((size_t)(b0 + row) * T_ + (t - 1)) * V_ + v] = ah[j] + bh;
                }
            }
        }
        if (t == T_) break;
        __syncthreads();

        // =========== phase B: gates -> h_new (bf16 pair) ==========
#pragma unroll
        for (int k4 = 0; k4 < 4; ++k4) {
            const int i = tid + k4 * NT_;
            if (i < R_ * E_) {
                const int r = i / E_, e = i - r * E_;
                const float gr = GIb[e * GSTR + r] + GHb[e * GSTR + r] + BSUM[e];
                const float gz = GIb[(E_ + e) * GSTR + r] + GHb[(E_ + e) * GSTR + r] + BSUM[E_ + e];
                const float gin = GIb[(E2_ + e) * GSTR + r] + BIN[e];
                const float ghn = GHb[(E2_ + e) * GSTR + r] + BHN[e];
                const float rg = sigmoid_f(gr);
                const float z = sigmoid_f(gz);
                const float nn = tanh_f(gin + rg * ghn);
                const float hold = bf2f(H1[r * HSTR + e]) + bf2f(H2[r * HSTR + e]);
                const float hnew = (1.0f - z) * nn + z * hold;
                const unsigned short h1 = f2bf(hnew);
                H1[r * HSTR + e] = h1;
                H2[r * HSTR + e] = f2bf(hnew - bf2f(h1));
            }
        }
        __syncthreads();

        // =========== phase C: cand MFMA + p-dot + LN stats ==========
        {
            float4v cc = (float4v){0.f, 0.f, 0.f, 0.f};
#pragma unroll
            for (int c = 0; c < WM_NC; ++c) {
                short8v a1 = *(const short8v*)&H1[frow * HSTR + c * 32 + fgrp * 8];
                short8v a2 = *(const short8v*)&H2[frow * HSTR + c * 32 + fgrp * 8];
                short8v bw1 = *(const short8v*)&ws[WS_WM + ((0 * WM_NT + wv) * WM_NC + c) * 512 + lane * 8];
                short8v bw2 = *(const short8v*)&ws[WS_WM + ((1 * WM_NT + wv) * WM_NC + c) * 512 + lane * 8];
                cc = __builtin_amdgcn_mfma_f32_16x16x32_bf16(a1, bw1, cc, 0, 0, 0);
                cc = __builtin_amdgcn_mfma_f32_16x16x32_bf16(a2, bw1, cc, 0, 0, 0);
                cc = __builtin_amdgcn_mfma_f32_16x16x32_bf16(a1, bw2, cc, 0, 0, 0);
            }
            const int col = wv * 16 + frow;  // cand col (0..127), reuse GIb
#pragma unroll
            for (int j = 0; j < 4; ++j) GIb[col * GSTR + fgrp * 4 + j] = cc[j];

            if (tid < 256) {
                const int r = tid >> 4, g = tid & 15;
                float s = 0.f;
                for (int e = g; e < E_; e += 16)
                    s += (bf2f(H1[r * HSTR + e]) + bf2f(H2[r * HSTR + e])) * WP[e];
                s += __shfl_xor(s, 1);
                s += __shfl_xor(s, 2);
                s += __shfl_xor(s, 4);
                s += __shfl_xor(s, 8);
                if (g == 0) Pp[r] = sigmoid_f(s + bp);
            } else {
                const int r = (tid - 256) >> 4, g = tid & 15;
                float s1 = 0.f, s2 = 0.f;
                for (int e = g; e < E_; e += 16) {
                    const float h = bf2f(H1[r * HSTR + e]) + bf2f(H2[r * HSTR + e]);
                    s1 += h;
                    s2 += h * h;
                }
                s1 += __shfl_xor(s1, 1);
                s1 += __shfl_xor(s1, 2);
                s1 += __shfl_xor(s1, 4);
                s1 += __shfl_xor(s1, 8);
                s2 += __shfl_xor(s2, 1);
                s2 += __shfl_xor(s2, 2);
                s2 += __shfl_xor(s2, 4);
                s2 += __shfl_xor(s2, 8);
                if (g == 0) {
                    const float mu = s1 * (1.0f / (float)E_);
                    const float var = s2 * (1.0f / (float)E_) - mu * mu;
                    MU[r] = mu;
                    RS[r] = rsqrtf(var + 1e-5f);
                }
            }
        }
        __syncthreads();

        // =========== phase D: m update, y = LN(h_new), embed t+1 ==========
#pragma unroll
        for (int k4 = 0; k4 < 4; ++k4) {
            const int i = tid + k4 * NT_;
            if (i < R_ * E_) {
                const int r = i / E_, e = i - r * E_;
                const float cand = tanh_f(GIb[e * GSTR + r] + BM[e]);
                const float pv = Pp[r];
                const float mold = bf2f(U1[r * USTR + E_ + e]) + bf2f(U2[r * USTR + E_ + e]);
                const float mnew = (1.0f - pv) * mold + pv * cand;
                const unsigned short m1 = f2bf(mnew);
                U1[r * USTR + E_ + e] = m1;
                U2[r * USTR + E_ + e] = f2bf(mnew - bf2f(m1));
                const float hv = bf2f(H1[r * HSTR + e]) + bf2f(H2[r * HSTR + e]);
                const float yv = (hv - MU[r]) * RS[r] * LNG[e] + LNB[e];
                const unsigned short y1 = f2bf(yv);
                Y1[r * HSTR + e] = y1;
                Y2[r * HSTR + e] = f2bf(yv - bf2f(y1));
            }
        }
        if (t + 1 < T_) {
#pragma unroll
            for (int k4 = 0; k4 < 4; ++k4) {
                const int i = tid + k4 * NT_;
                if (i < R_ * E_) {
                    const int r = i / E_, e = i - r * E_;
                    const int token = IDX[r * T_ + t + 1];
                    const float x = tok[token * E_ + e] + pos[(t + 1) * E_ + e];
                    const unsigned short x1 = f2bf(x);
                    U1[r * USTR + e] = x1;
                    U2[r * USTR + e] = f2bf(x - bf2f(x1));
                }
            }
        }
        __syncthreads();
    }
}

extern "C" void kernel_launch(void* const* d_in, const int* in_sizes, int n_in,
                              void* d_out, int out_size, void* d_ws, size_t ws_size,
                              hipStream_t stream) {
    const int* idx = (const int*)d_in[0];
    const float* tok = (const float*)d_in[1];
    const float* pos = (const float*)d_in[2];
    const float* w_ih = (const float*)d_in[3];
    const float* w_hh = (const float*)d_in[4];
    const float* b_ih = (const float*)d_in[5];
    const float* b_hh = (const float*)d_in[6];
    const float* w_p = (const float*)d_in[7];
    const float* b_p = (const float*)d_in[8];
    const float* w_m = (const float*)d_in[9];
    const float* b_m = (const float*)d_in[10];
    const float* ln_g = (const float*)d_in[11];
    const float* ln_b = (const float*)d_in[12];
    const float* w_head = (const float*)d_in[13];
    const float* b_head = (const float*)d_in[14];
    float* out = (float*)d_out;
    unsigned short* ws = (unsigned short*)d_ws;

    prep_weights<<<512, 256, 0, stream>>>(w_ih, w_hh, w_m, w_head, ws);

    (void)hipFuncSetAttribute((const void*)gru_main,
                              hipFuncAttributeMaxDynamicSharedMemorySize,
                              SMEM_BYTES);
    gru_main<<<NB_, NT_, SMEM_BYTES, stream>>>(idx, tok, pos, b_ih, b_hh, w_p, b_p,
                                               b_m, ln_g, ln_b, b_head, ws, out);
}

// Round 4
// 3023.635 us; speedup vs baseline: 3.5978x; 1.0725x over previous
//
#include <hip/hip_runtime.h>
#include <math.h>

// Problem constants
#define B_   2048
#define T_   256
#define E_   124
#define V_   65
#define E2_  248
#define E3_  372
#define R_   8               // batch rows per block; packed-M uses rows 0-7=x1, 8-15=x2
#define NT_  512             // 8 waves
#define NB_  (B_ / R_)       // 256 blocks -> 1 block on every CU

// fragment geometry (16x16x32 MFMA tiles) — ws layout identical to Round 3
#define GI_NT 24   // 384 cols  (372 padded)
#define GI_NC 8    // K=256     (248 padded)
#define GH_NT 24
#define GH_NC 4    // K=128     (124 padded)
#define WM_NT 8    // 128 cols
#define WM_NC 4
#define HD_NT 5    // 80 cols   (65 padded)
#define HD_NC 4

// ws offsets (unsigned short elements); each frag block = 512 bf16 = 1KB
#define WS_GI 0
#define WS_GH (WS_GI + 2 * GI_NT * GI_NC * 512)   // 196608
#define WS_WM (WS_GH + 2 * GH_NT * GH_NC * 512)   // 294912
#define WS_HD (WS_WM + 2 * WM_NT * WM_NC * 512)   // 327680
#define WS_END (WS_HD + 2 * HD_NT * HD_NC * 512)  // 348160 shorts = 680KB

// LDS byte offsets (all 16B aligned)
#define USTR 264   // u row stride in shorts (x 0:124 | m 124:248 | pad)
#define HSTR 136   // h/y row stride in shorts
#define GSTR 9     // gate buffer col stride in floats (rows 0..7, odd stride)
#define L_U1 0          // 8*264*2 = 4224
#define L_U2 4224
#define L_H1 8448       // 8*136*2 = 2176
#define L_H2 10624
#define L_Y1 12800
#define L_Y2 14976
#define L_GI 17152      // 384*9*4 = 13824
#define L_GH 30976
#define L_BSUM 44800    // 248 f
#define L_BIN  45792    // 124 f
#define L_BHN  46288
#define L_BM   46784
#define L_WP   47280
#define L_LNG  47776
#define L_LNB  48272
#define L_BHD  48768    // 65 f (pad)
#define L_P    49040    // 8 f
#define L_MU   49072
#define L_RS   49104
#define L_IDX  49136    // 8*256 int = 8192
#define SMEM_BYTES 57344

typedef __attribute__((ext_vector_type(8))) short short8v;
typedef __attribute__((ext_vector_type(4))) float float4v;

__device__ __forceinline__ unsigned short f2bf(float x) {
    unsigned u = __float_as_uint(x);
    unsigned r = (u + 0x7fffu + ((u >> 16) & 1u)) >> 16;
    return (unsigned short)r;
}
__device__ __forceinline__ float bf2f(unsigned short s) {
    return __uint_as_float(((unsigned)s) << 16);
}
__device__ __forceinline__ float sigmoid_f(float x) {
    return 1.0f / (1.0f + __expf(-x));
}
__device__ __forceinline__ float tanh_f(float x) {
    return 2.0f / (1.0f + __expf(-2.0f * x)) - 1.0f;
}

// Build bf16 split-2 B-fragments for all weight matrices (same as Round 3).
// Frag block (mat, split, tile, chunk): 512 bf16; lane l, reg j holds
// W[col = tile*16 + (l&15)][k = chunk*32 + (l>>4)*8 + j]  (zero-padded).
__global__ void prep_weights(const float* __restrict__ w_ih,
                             const float* __restrict__ w_hh,
                             const float* __restrict__ w_m,
                             const float* __restrict__ w_head,
                             unsigned short* __restrict__ ws) {
    for (int n = blockIdx.x * blockDim.x + threadIdx.x; n < WS_END;
         n += gridDim.x * blockDim.x) {
        int base, nc, nt, Kreal, Creal, ld;
        const float* src;
        if (n < WS_GH)      { base = WS_GI; nc = GI_NC; nt = GI_NT; Kreal = E2_; Creal = E3_; ld = E2_; src = w_ih; }
        else if (n < WS_WM) { base = WS_GH; nc = GH_NC; nt = GH_NT; Kreal = E_;  Creal = E3_; ld = E_;  src = w_hh; }
        else if (n < WS_HD) { base = WS_WM; nc = WM_NC; nt = WM_NT; Kreal = E_;  Creal = E_;  ld = E_;  src = w_m; }
        else                { base = WS_HD; nc = HD_NC; nt = HD_NT; Kreal = E_;  Creal = V_;  ld = E_;  src = w_head; }
        int m = n - base;
        int blk = m >> 9, r9 = m & 511;
        int lane = r9 >> 3, j = r9 & 7;
        int c = blk % nc;
        int rest = blk / nc;
        int tile = rest % nt;
        int split = rest / nt;
        int k = c * 32 + (lane >> 4) * 8 + j;
        int col = tile * 16 + (lane & 15);
        float w = (k < Kreal && col < Creal) ? src[col * ld + k] : 0.0f;
        unsigned short w1 = f2bf(w);
        ws[n] = (split == 0) ? w1 : f2bf(w - bf2f(w1));
    }
}

__global__ void __launch_bounds__(NT_, 2)
gru_main(const int* __restrict__ idx, const float* __restrict__ tok,
         const float* __restrict__ pos,
         const float* __restrict__ b_ih, const float* __restrict__ b_hh,
         const float* __restrict__ w_p, const float* __restrict__ b_p,
         const float* __restrict__ b_m,
         const float* __restrict__ ln_g, const float* __restrict__ ln_b,
         const float* __restrict__ b_head,
         const unsigned short* __restrict__ ws, float* __restrict__ out) {
    extern __shared__ char smraw[];
    unsigned short* U1 = (unsigned short*)(smraw + L_U1);
    unsigned short* U2 = (unsigned short*)(smraw + L_U2);
    unsigned short* H1 = (unsigned short*)(smraw + L_H1);
    unsigned short* H2 = (unsigned short*)(smraw + L_H2);
    unsigned short* Y1 = (unsigned short*)(smraw + L_Y1);
    unsigned short* Y2 = (unsigned short*)(smraw + L_Y2);
    float* GIb = (float*)(smraw + L_GI);
    float* GHb = (float*)(smraw + L_GH);
    float* BSUM = (float*)(smraw + L_BSUM);
    float* BIN = (float*)(smraw + L_BIN);
    float* BHN = (float*)(smraw + L_BHN);
    float* BM = (float*)(smraw + L_BM);
    float* WP = (float*)(smraw + L_WP);
    float* LNG = (float*)(smraw + L_LNG);
    float* LNB = (float*)(smraw + L_LNB);
    float* BHD = (float*)(smraw + L_BHD);
    float* Pp = (float*)(smraw + L_P);
    float* MU = (float*)(smraw + L_MU);
    float* RS = (float*)(smraw + L_RS);
    int* IDX = (int*)(smraw + L_IDX);

    const int tid = threadIdx.x;
    const int lane = tid & 63;
    const int wv = tid >> 6;
    const int b0 = blockIdx.x * R_;
    const int frow = lane & 15;   // A row (0-7:x1, 8-15:x2) / B col / C col
    const int fgrp = lane >> 4;   // k-group / C row-group

    // ---- one-time staging ----
    for (int i = tid; i < E2_; i += NT_) BSUM[i] = b_ih[i] + b_hh[i];
    for (int i = tid; i < E_; i += NT_) {
        BIN[i] = b_ih[E2_ + i];
        BHN[i] = b_hh[E2_ + i];
        BM[i] = b_m[i];
        WP[i] = w_p[i];
        LNG[i] = ln_g[i];
        LNB[i] = ln_b[i];
    }
    for (int i = tid; i < V_; i += NT_) BHD[i] = b_head[i];
    for (int i = tid; i < R_ * T_; i += NT_) IDX[i] = idx[b0 * T_ + i];
    for (int i = tid; i < R_ * USTR; i += NT_) { U1[i] = 0; U2[i] = 0; }
    for (int i = tid; i < R_ * HSTR; i += NT_) { H1[i] = 0; H2[i] = 0; Y1[i] = 0; Y2[i] = 0; }
    const float bp = b_p[0];

    // register-cache w_hh fragments (t-invariant): 24 frags = 96 VGPR/lane
    short8v ghf1[3][4], ghf2[3][4];
#pragma unroll
    for (int ti = 0; ti < 3; ++ti) {
#pragma unroll
        for (int c = 0; c < GH_NC; ++c) {
            ghf1[ti][c] = *(const short8v*)&ws[WS_GH + ((wv * 3 + ti) * GH_NC + c) * 512 + lane * 8];
            ghf2[ti][c] = *(const short8v*)&ws[WS_GH + ((GH_NT + wv * 3 + ti) * GH_NC + c) * 512 + lane * 8];
        }
    }

    // per-lane packed-M source rows
    const unsigned short* Urow = (frow < 8 ? U1 : U2) + (frow & 7) * USTR;
    const unsigned short* Hrow = (frow < 8 ? H1 : H2) + (frow & 7) * HSTR;
    const unsigned short* Yrow = (frow < 8 ? Y1 : Y2) + (frow & 7) * HSTR;
    __syncthreads();

    // embed t=0 into u[x]
#pragma unroll
    for (int k4 = 0; k4 < 2; ++k4) {
        const int i = tid + k4 * NT_;
        if (i < R_ * E_) {
            const int r = i & 7, e = i >> 3;
            const int token = IDX[r * T_];
            const float x = tok[token * E_ + e] + pos[e];
            const unsigned short x1 = f2bf(x);
            U1[r * USTR + e] = x1;
            U2[r * USTR + e] = f2bf(x - bf2f(x1));
        }
    }
    __syncthreads();

    for (int t = 0; t <= T_; ++t) {
        // ===== phase A: gi/gh MFMAs (t<T) + head MFMA for t-1 =====
        if (t < T_) {
            float4v acc[3], accg[3];
#pragma unroll
            for (int ti = 0; ti < 3; ++ti) {
                acc[ti] = (float4v){0.f, 0.f, 0.f, 0.f};
                accg[ti] = (float4v){0.f, 0.f, 0.f, 0.f};
            }
            // gi: [x;m] @ w_ih^T  (K=256; 2 mfma per tile-chunk, packed-M split)
#pragma unroll
            for (int c = 0; c < GI_NC; ++c) {
                const short8v a = *(const short8v*)&Urow[c * 32 + fgrp * 8];
#pragma unroll
                for (int ti = 0; ti < 3; ++ti) {
                    const int tile = wv * 3 + ti;
                    const short8v b1 = *(const short8v*)&ws[WS_GI + (tile * GI_NC + c) * 512 + lane * 8];
                    const short8v b2 = *(const short8v*)&ws[WS_GI + ((GI_NT + tile) * GI_NC + c) * 512 + lane * 8];
                    acc[ti] = __builtin_amdgcn_mfma_f32_16x16x32_bf16(a, b1, acc[ti], 0, 0, 0);
                    acc[ti] = __builtin_amdgcn_mfma_f32_16x16x32_bf16(a, b2, acc[ti], 0, 0, 0);
                }
            }
            // gh: h @ w_hh^T  (K=128; reg-cached B frags)
#pragma unroll
            for (int c = 0; c < GH_NC; ++c) {
                const short8v a = *(const short8v*)&Hrow[c * 32 + fgrp * 8];
#pragma unroll
                for (int ti = 0; ti < 3; ++ti) {
                    accg[ti] = __builtin_amdgcn_mfma_f32_16x16x32_bf16(a, ghf1[ti][c], accg[ti], 0, 0, 0);
                    accg[ti] = __builtin_amdgcn_mfma_f32_16x16x32_bf16(a, ghf2[ti][c], accg[ti], 0, 0, 0);
                }
            }
            // combine split rows (r & r+8) and write rows 0..7
#pragma unroll
            for (int ti = 0; ti < 3; ++ti) {
                const int col = (wv * 3 + ti) * 16 + frow;
#pragma unroll
                for (int j = 0; j < 4; ++j) {
                    const float vi = acc[ti][j] + __shfl_xor(acc[ti][j], 32);
                    const float vh = accg[ti][j] + __shfl_xor(accg[ti][j], 32);
                    if (fgrp < 2) {
                        GIb[col * GSTR + fgrp * 4 + j] = vi;
                        GHb[col * GSTR + fgrp * 4 + j] = vh;
                    }
                }
            }
        }
        // head for step t-1 (y from phase D of t-1)
        if (t > 0 && wv < HD_NT) {
            float4v ah = (float4v){0.f, 0.f, 0.f, 0.f};
#pragma unroll
            for (int c = 0; c < HD_NC; ++c) {
                const short8v a = *(const short8v*)&Yrow[c * 32 + fgrp * 8];
                const short8v b1 = *(const short8v*)&ws[WS_HD + (wv * HD_NC + c) * 512 + lane * 8];
                const short8v b2 = *(const short8v*)&ws[WS_HD + ((HD_NT + wv) * HD_NC + c) * 512 + lane * 8];
                ah = __builtin_amdgcn_mfma_f32_16x16x32_bf16(a, b1, ah, 0, 0, 0);
                ah = __builtin_amdgcn_mfma_f32_16x16x32_bf16(a, b2, ah, 0, 0, 0);
            }
            const int v = wv * 16 + frow;
#pragma unroll
            for (int j = 0; j < 4; ++j) {
                const float val = ah[j] + __shfl_xor(ah[j], 32);
                if (fgrp < 2 && v < V_) {
                    const int row = fgrp * 4 + j;
                    __builtin_nontemporal_store(
                        val + BHD[v], &out[((size_t)(b0 + row) * T_ + (t - 1)) * V_ + v]);
                }
            }
        }
        if (t == T_) break;
        __syncthreads();

        // ===== phase B: gates -> h_new (bf16 pair) =====
#pragma unroll
        for (int k4 = 0; k4 < 2; ++k4) {
            const int i = tid + k4 * NT_;
            if (i < R_ * E_) {
                const int r = i & 7, e = i >> 3;
                const float gr = GIb[e * GSTR + r] + GHb[e * GSTR + r] + BSUM[e];
                const float gz = GIb[(E_ + e) * GSTR + r] + GHb[(E_ + e) * GSTR + r] + BSUM[E_ + e];
                const float gin = GIb[(E2_ + e) * GSTR + r] + BIN[e];
                const float ghn = GHb[(E2_ + e) * GSTR + r] + BHN[e];
                const float rg = sigmoid_f(gr);
                const float z = sigmoid_f(gz);
                const float nn = tanh_f(gin + rg * ghn);
                const float hold = bf2f(H1[r * HSTR + e]) + bf2f(H2[r * HSTR + e]);
                const float hnew = (1.0f - z) * nn + z * hold;
                const unsigned short h1 = f2bf(hnew);
                H1[r * HSTR + e] = h1;
                H2[r * HSTR + e] = f2bf(hnew - bf2f(h1));
            }
        }
        __syncthreads();

        // ===== phase C: cand MFMA + p-dot + LN stats =====
        {
            float4v cc = (float4v){0.f, 0.f, 0.f, 0.f};
#pragma unroll
            for (int c = 0; c < WM_NC; ++c) {
                const short8v a = *(const short8v*)&Hrow[c * 32 + fgrp * 8];
                const short8v b1 = *(const short8v*)&ws[WS_WM + (wv * WM_NC + c) * 512 + lane * 8];
                const short8v b2 = *(const short8v*)&ws[WS_WM + ((WM_NT + wv) * WM_NC + c) * 512 + lane * 8];
                cc = __builtin_amdgcn_mfma_f32_16x16x32_bf16(a, b1, cc, 0, 0, 0);
                cc = __builtin_amdgcn_mfma_f32_16x16x32_bf16(a, b2, cc, 0, 0, 0);
            }
            const int col = wv * 16 + frow;  // cand col (0..127), reuse GIb
#pragma unroll
            for (int j = 0; j < 4; ++j) {
                const float v = cc[j] + __shfl_xor(cc[j], 32);
                if (fgrp < 2) GIb[col * GSTR + fgrp * 4 + j] = v;
            }
            if (tid < 128) {
                const int r = tid >> 4, g = tid & 15;
                float s = 0.f;
                for (int e = g; e < E_; e += 16)
                    s += (bf2f(H1[r * HSTR + e]) + bf2f(H2[r * HSTR + e])) * WP[e];
                s += __shfl_xor(s, 1);
                s += __shfl_xor(s, 2);
                s += __shfl_xor(s, 4);
                s += __shfl_xor(s, 8);
                if (g == 0) Pp[r] = sigmoid_f(s + bp);
            } else if (tid < 256) {
                const int r = (tid - 128) >> 4, g = tid & 15;
                float s1 = 0.f, s2 = 0.f;
                for (int e = g; e < E_; e += 16) {
                    const float h = bf2f(H1[r * HSTR + e]) + bf2f(H2[r * HSTR + e]);
                    s1 += h;
                    s2 += h * h;
                }
                s1 += __shfl_xor(s1, 1);
                s1 += __shfl_xor(s1, 2);
                s1 += __shfl_xor(s1, 4);
                s1 += __shfl_xor(s1, 8);
                s2 += __shfl_xor(s2, 1);
                s2 += __shfl_xor(s2, 2);
                s2 += __shfl_xor(s2, 4);
                s2 += __shfl_xor(s2, 8);
                if (g == 0) {
                    const float mu = s1 * (1.0f / (float)E_);
                    const float var = s2 * (1.0f / (float)E_) - mu * mu;
                    MU[r] = mu;
                    RS[r] = rsqrtf(var + 1e-5f);
                }
            }
        }
        __syncthreads();

        // ===== phase D: m update, y = LN(h_new), embed t+1 =====
#pragma unroll
        for (int k4 = 0; k4 < 2; ++k4) {
            const int i = tid + k4 * NT_;
            if (i < R_ * E_) {
                const int r = i & 7, e = i >> 3;
                const float cand = tanh_f(GIb[e * GSTR + r] + BM[e]);
                const float pv = Pp[r];
                const float mold = bf2f(U1[r * USTR + E_ + e]) + bf2f(U2[r * USTR + E_ + e]);
                const float mnew = (1.0f - pv) * mold + pv * cand;
                const unsigned short m1 = f2bf(mnew);
                U1[r * USTR + E_ + e] = m1;
                U2[r * USTR + E_ + e] = f2bf(mnew - bf2f(m1));
                const float hv = bf2f(H1[r * HSTR + e]) + bf2f(H2[r * HSTR + e]);
                const float yv = (hv - MU[r]) * RS[r] * LNG[e] + LNB[e];
                const unsigned short y1 = f2bf(yv);
                Y1[r * HSTR + e] = y1;
                Y2[r * HSTR + e] = f2bf(yv - bf2f(y1));
            }
        }
        if (t + 1 < T_) {
#pragma unroll
            for (int k4 = 0; k4 < 2; ++k4) {
                const int i = tid + k4 * NT_;
                if (i < R_ * E_) {
                    const int r = i & 7, e = i >> 3;
                    const int token = IDX[r * T_ + t + 1];
                    const float x = tok[token * E_ + e] + pos[(t + 1) * E_ + e];
                    const unsigned short x1 = f2bf(x);
                    U1[r * USTR + e] = x1;
                    U2[r * USTR + e] = f2bf(x - bf2f(x1));
                }
            }
        }
        __syncthreads();
    }
}

extern "C" void kernel_launch(void* const* d_in, const int* in_sizes, int n_in,
                              void* d_out, int out_size, void* d_ws, size_t ws_size,
                              hipStream_t stream) {
    const int* idx = (const int*)d_in[0];
    const float* tok = (const float*)d_in[1];
    const float* pos = (const float*)d_in[2];
    const float* w_ih = (const float*)d_in[3];
    const float* w_hh = (const float*)d_in[4];
    const float* b_ih = (const float*)d_in[5];
    const float* b_hh = (const float*)d_in[6];
    const float* w_p = (const float*)d_in[7];
    const float* b_p = (const float*)d_in[8];
    const float* w_m = (const float*)d_in[9];
    const float* b_m = (const float*)d_in[10];
    const float* ln_g = (const float*)d_in[11];
    const float* ln_b = (const float*)d_in[12];
    const float* w_head = (const float*)d_in[13];
    const float* b_head = (const float*)d_in[14];
    float* out = (float*)d_out;
    unsigned short* ws = (unsigned short*)d_ws;

    prep_weights<<<512, 256, 0, stream>>>(w_ih, w_hh, w_m, w_head, ws);

    (void)hipFuncSetAttribute((const void*)gru_main,
                              hipFuncAttributeMaxDynamicSharedMemorySize,
                              SMEM_BYTES);
    gru_main<<<NB_, NT_, SMEM_BYTES, stream>>>(idx, tok, pos, b_ih, b_hh, w_p, b_p,
                                               b_m, ln_g, ln_b, b_head, ws, out);
}